// Round 5
// baseline (363.642 us; speedup 1.0000x reference)
//
#include <hip/hip_runtime.h>

#define BB 64
#define TT 1024
#define BT (BB * TT)
#define HH 512
#define KMIX 10
#define UU 64
#define VV 80
#define SDIM 3
#define OUTW 595
#define ROWS 16

// ---------------- kW: transpose W [512,30] -> Wt [30,512] (tiny, once) ----------------
__global__ __launch_bounds__(256) void kW_transpose(const float* __restrict__ Wm, float* __restrict__ Wt) {
    int idx = blockIdx.x * 256 + threadIdx.x;
    if (idx < 30 * HH) {
        int j = idx >> 9, h = idx & 511;
        Wt[idx] = Wm[h * 30 + j];
    }
}

// ---------------- k1: abk_t = exp(X@Wt^T + b) (transposed [30][BT]); fused x/stroke copy ----------------
__global__ __launch_bounds__(512) void k1_gemm(
    const float* __restrict__ x,       // [BT, H]
    const float* __restrict__ stroke,  // [BT, 3]
    const float* __restrict__ Wt,      // [30, 512]
    const float* __restrict__ bias,    // [30]
    float* __restrict__ out,           // [BT, 595]
    float* __restrict__ abk_t)         // [30, BT]
{
    __shared__ float xs[ROWS][HH + 4];  // 33 KB; reused for partials
    const int tid = threadIdx.x;
    const int r0 = blockIdx.x * ROWS;

    // Stage X tile; store x-part directly from registers (L2 merges 16B-stride lanes: R2 evidence).
    const float4* x4 = (const float4*)(x + (size_t)r0 * HH);
    #pragma unroll
    for (int i = 0; i < 4; ++i) {
        int f4 = tid + (i << 9);
        int row = f4 >> 7;
        int col = (f4 & 127) << 2;
        float4 v = x4[f4];
        *(float4*)&xs[row][col] = v;
        float* orow = out + (size_t)(r0 + row) * OUTW + col;
        orow[0] = v.x; orow[1] = v.y; orow[2] = v.z; orow[3] = v.w;
    }
    if (tid < ROWS * SDIM) {
        int row = tid / SDIM, c = tid % SDIM;
        out[(size_t)(r0 + row) * OUTW + HH + VV + c] = stroke[(size_t)(r0 + row) * SDIM + c];
    }
    __syncthreads();

    // GEMM partials: thread = (hc 0..15, j 0..29); W chunk (32 floats) in registers, reused 16 rows.
    const bool active = tid < 480;
    float acc[ROWS];
    if (active) {
        int hc = tid / 30, j = tid % 30;
        const float4* wp = (const float4*)(Wt + j * HH + hc * 32);
        float4 w4[8];
        #pragma unroll
        for (int q = 0; q < 8; ++q) w4[q] = wp[q];
        #pragma unroll
        for (int r = 0; r < ROWS; ++r) {
            const float4* xp = (const float4*)&xs[r][(tid / 30) * 32];
            float s = 0.f;
            #pragma unroll
            for (int q = 0; q < 8; ++q) {
                float4 xv = xp[q];
                s += xv.x * w4[q].x + xv.y * w4[q].y + xv.z * w4[q].z + xv.w * w4[q].w;
            }
            acc[r] = s;
        }
    }
    __syncthreads();                 // xs reads done -> reuse as partial buffer
    float* plds = &xs[0][0];         // [r][hc][j] = r*480 + hc*30 + j
    if (active) {
        #pragma unroll
        for (int r = 0; r < ROWS; ++r) plds[r * 480 + tid] = acc[r];
    }
    __syncthreads();
    if (active) {
        int row = tid & 15, jj = tid >> 4;   // jj 0..29: per-instr stores fill whole 64B lines per j-stream
        float s = 0.f;
        #pragma unroll
        for (int q = 0; q < 16; ++q) s += plds[row * 480 + q * 30 + jj];
        abk_t[(size_t)jj * BT + r0 + row] = expf(s + bias[jj]);
    }
}

// ---------------- k2: prefix-scan over T per (b,k) on contiguous rows of abk_t ----------------
__global__ __launch_bounds__(64) void k2_scan(
    float* __restrict__ abk_t, const float* __restrict__ kappa0)
{
    const int b = blockIdx.x / KMIX;
    const int k = blockIdx.x % KMIX;
    const int lane = threadIdx.x;
    float4* p4 = (float4*)(abk_t + (size_t)(20 + k) * BT + b * TT);  // 1024 contiguous floats

    float v[16];
    #pragma unroll
    for (int i = 0; i < 4; ++i) {
        float4 q = p4[lane * 4 + i];
        v[i * 4 + 0] = q.x; v[i * 4 + 1] = q.y; v[i * 4 + 2] = q.z; v[i * 4 + 3] = q.w;
    }
    #pragma unroll
    for (int i = 1; i < 16; ++i) v[i] += v[i - 1];

    float total = v[15], xinc = total;
    #pragma unroll
    for (int off = 1; off < 64; off <<= 1) {
        float y = __shfl_up(xinc, off, 64);
        if (lane >= off) xinc += y;
    }
    float excl = xinc - total + kappa0[b * KMIX + k];

    #pragma unroll
    for (int i = 0; i < 4; ++i) {
        float4 q;
        q.x = v[i * 4 + 0] + excl; q.y = v[i * 4 + 1] + excl;
        q.z = v[i * 4 + 2] + excl; q.w = v[i * 4 + 3] + excl;
        p4[lane * 4 + i] = q;
    }
}

// ---------------- k3: lane = t. phi[64] in registers; char rows broadcast from LDS ----------------
__global__ __launch_bounds__(256) void k3_window(
    const float* __restrict__ abk_t,  // [30, BT] (kappa rows cumulative)
    const float* __restrict__ ch,     // [B, U, V]
    float* __restrict__ out)          // [BT, 595]
{
    __shared__ float cst[VV][68];        // char transposed [v][u]: 21.8 KB
    __shared__ float win[4][UU * 81];    // per-wave output staging, stride 81 (odd): 83 KB
    const int b = blockIdx.x >> 2;
    const int qtr = blockIdx.x & 3;
    const int tid = threadIdx.x;
    const int wave = tid >> 6, lane = tid & 63;

    // Stage char transposed (80%4==0: float4 never crosses a u row)
    const float4* c4 = (const float4*)(ch + (size_t)b * UU * VV);
    #pragma unroll
    for (int i = 0; i < 5; ++i) {
        int f4 = tid + i * 256;
        float4 v = c4[f4];
        int f = f4 * 4;
        int u = f / 80;
        int v0 = f - u * 80;
        cst[v0][u] = v.x; cst[v0 + 1][u] = v.y; cst[v0 + 2][u] = v.z; cst[v0 + 3][u] = v.w;
    }
    __syncthreads();

    const int rb = b * TT + qtr * 256 + wave * 64;  // wave's 64 t-rows; this lane owns row rb+lane

    // 30 coalesced global loads: this t's alpha/beta/kappa
    float ab[30];
    #pragma unroll
    for (int j = 0; j < 30; ++j) ab[j] = abk_t[(size_t)j * BT + rb + lane];

    // phi[u] for u=0..63, all in registers
    float phi[UU];
    #pragma unroll
    for (int u = 0; u < UU; ++u) {
        float s = 0.f;
        const float uf = (float)u;
        #pragma unroll
        for (int k = 0; k < KMIX; ++k) {
            float d = ab[20 + k] - uf;
            s += ab[k] * __expf(-ab[10 + k] * d * d);
        }
        phi[u] = s;
    }

    // window[v] = sum_u phi[u] * cst[v][u]; cst row = 16 broadcast b128 reads shared by all 64 t's
    float* winw = win[wave];
    for (int v = 0; v < VV; ++v) {
        float a = 0.f;
        #pragma unroll
        for (int q = 0; q < 16; ++q) {
            float4 cq = *(const float4*)&cst[v][q * 4];
            a += phi[q * 4 + 0] * cq.x + phi[q * 4 + 1] * cq.y
               + phi[q * 4 + 2] * cq.z + phi[q * 4 + 3] * cq.w;
        }
        winw[lane * 81 + v] = a;   // stride 81: conflict-free
    }

    // Coalesced flush (same wave: no barrier needed)
    for (int i = lane; i < UU * VV; i += 64) {
        int t = i / 80, v = i - t * 80;
        out[(size_t)(rb + t) * OUTW + HH + v] = winw[t * 81 + v];
    }
}

extern "C" void kernel_launch(void* const* d_in, const int* in_sizes, int n_in,
                              void* d_out, int out_size, void* d_ws, size_t ws_size,
                              hipStream_t stream) {
    const float* input0   = (const float*)d_in[0];
    const float* stroke   = (const float*)d_in[1];
    const float* chars    = (const float*)d_in[2];
    const float* window_w = (const float*)d_in[3];
    const float* window_b = (const float*)d_in[4];
    const float* kappa0   = (const float*)d_in[5];
    float* out   = (float*)d_out;
    float* abk_t = (float*)d_ws;                                     // [30][BT] = 7.86 MB
    float* Wt    = (float*)((char*)d_ws + (size_t)30 * BT * 4);      // [30][512] = 61 KB

    kW_transpose<<<dim3((30 * HH + 255) / 256), dim3(256), 0, stream>>>(window_w, Wt);
    k1_gemm<<<dim3(BT / ROWS), dim3(512), 0, stream>>>(input0, stroke, Wt, window_b, out, abk_t);
    k2_scan<<<dim3(BB * KMIX), dim3(64), 0, stream>>>(abk_t, kappa0);
    k3_window<<<dim3(BB * 4), dim3(256), 0, stream>>>(abk_t, chars, out);
}